// Round 11
// baseline (288.034 us; speedup 1.0000x reference)
//
#include <hip/hip_runtime.h>
#include <hip/hip_bf16.h>
#include <math.h>

#define HIDDEN 2048
#define HARM   64
#define NHEADS 16
#define HDIM   128
#define SEQ    2048
#define BATCH  2
#define ROWS   (BATCH*SEQ)   // 4096
#define RN     (ROWS*HARM)   // 262144 (one K-chunk partial plane)
#define PN     ((size_t)ROWS*HIDDEN)  // 8388608

using bf16x8 = __attribute__((ext_vector_type(8))) short;
using f32x16 = __attribute__((ext_vector_type(16))) float;

// hi/lo double-bf16 split: a ~= hi + lo with ~16-bit effective mantissa
__device__ inline void split_bf(float a, ushort& hi, ushort& lo) {
  __hip_bfloat16 h = __float2bfloat16(a);
  float hf = __bfloat162float(h);
  __hip_bfloat16 l = __float2bfloat16(a - hf);
  union { __hip_bfloat16 b; ushort u; } c1, c2;
  c1.b = h; c2.b = l;
  hi = c1.u; lo = c2.u;
}

__device__ inline void split4(float4 v, ushort4& h, ushort4& l) {
  split_bf(v.x, h.x, l.x); split_bf(v.y, h.y, l.y);
  split_bf(v.z, h.z, l.z); split_bf(v.w, h.w, l.w);
}

// ---------------- prep: w = amp*cos(phase) hi/lo for all 4 sets (grid 2048)
__global__ __launch_bounds__(256) void prep_w(
    const float* __restrict__ pq, const float* __restrict__ aq,
    const float* __restrict__ pk, const float* __restrict__ ak,
    const float* __restrict__ pv, const float* __restrict__ av,
    const float* __restrict__ po, const float* __restrict__ ao,
    ushort* __restrict__ Wh, ushort* __restrict__ Wl) {
  int i = blockIdx.x * 256 + threadIdx.x;
  const int N = HIDDEN * HARM;
  int set = i / N, j = i - set * N;
  const float* p = (set == 0) ? pq : (set == 1) ? pk : (set == 2) ? pv : po;
  const float* a = (set == 0) ? aq : (set == 1) ? ak : (set == 2) ? av : ao;
  float wv = a[j] * cosf(p[j]);
  ushort h, l;
  split_bf(wv, h, l);
  size_t o = (size_t)set * N + j;
  Wh[o] = h; Wl[o] = l;
}

// --------------- MFMA resonance, fp32 inputs split inline, software-pipelined.
// Rp[kc][M][64] = X * basis^T. grid (64 Mtiles, 4 Kchunks of 512, 3 bases).
__global__ __launch_bounds__(256) void gemm_res_f32(
    const float* __restrict__ X,
    const float* __restrict__ b0, const float* __restrict__ b1,
    const float* __restrict__ b2,
    float* __restrict__ R0, float* __restrict__ R1, float* __restrict__ R2) {
  const int z = blockIdx.z;
  const float* B = (z == 0) ? b0 : (z == 1) ? b1 : b2;
  float* Rp = (z == 0) ? R0 : (z == 1) ? R1 : R2;
  const int row0 = blockIdx.x * 64;
  const int kc = blockIdx.y;
  __shared__ __align__(16) ushort Xs[2][2][64][72];   // [buf][hi/lo][row][k] 36 KB
  __shared__ __align__(16) ushort Bs[2][2][64][72];   // 36 KB
  const int t = threadIdx.x;
  const int lane = t & 63, w = t >> 6;
  const int l31 = lane & 31, hh = lane >> 5;
  const int m0 = (w & 1) * 32, n0 = (w >> 1) * 32;
  const int srow = t >> 2;
  const int sc = (t & 3) * 16;
  const size_t xrow = (size_t)(row0 + srow) * HIDDEN + sc;
  const size_t brow = (size_t)srow * HIDDEN + sc;
  f32x16 acc;
  #pragma unroll
  for (int j = 0; j < 16; ++j) acc[j] = 0.0f;

  float4 xr[4], br[4];
  const int kbase = kc * 512;

  // prologue: load + split + store chunk 0 into buffer 0
  {
    const float* xp = X + xrow + kbase;
    const float* bp = B + brow + kbase;
    #pragma unroll
    for (int e = 0; e < 4; ++e) { xr[e] = *(const float4*)&xp[e * 4]; br[e] = *(const float4*)&bp[e * 4]; }
    #pragma unroll
    for (int e = 0; e < 4; ++e) {
      ushort4 xh, xl, bh, bl;
      split4(xr[e], xh, xl); split4(br[e], bh, bl);
      *(ushort4*)&Xs[0][0][srow][sc + e * 4] = xh;
      *(ushort4*)&Xs[0][1][srow][sc + e * 4] = xl;
      *(ushort4*)&Bs[0][0][srow][sc + e * 4] = bh;
      *(ushort4*)&Bs[0][1][srow][sc + e * 4] = bl;
    }
  }
  __syncthreads();

  for (int it = 0; it < 8; ++it) {
    // issue prefetch for next chunk (last iter redundantly reloads itself)
    {
      const int kn = kbase + ((it < 7) ? (it + 1) : it) * 64;
      const float* xp = X + xrow + kn;
      const float* bp = B + brow + kn;
      #pragma unroll
      for (int e = 0; e < 4; ++e) { xr[e] = *(const float4*)&xp[e * 4]; br[e] = *(const float4*)&bp[e * 4]; }
    }
    const int cb = it & 1;
    #pragma unroll
    for (int ks = 0; ks < 4; ++ks) {
      bf16x8 ah = *(const bf16x8*)&Xs[cb][0][m0 + l31][ks * 16 + 8 * hh];
      bf16x8 al = *(const bf16x8*)&Xs[cb][1][m0 + l31][ks * 16 + 8 * hh];
      bf16x8 bh = *(const bf16x8*)&Bs[cb][0][n0 + l31][ks * 16 + 8 * hh];
      bf16x8 bl = *(const bf16x8*)&Bs[cb][1][n0 + l31][ks * 16 + 8 * hh];
      acc = __builtin_amdgcn_mfma_f32_32x32x16_bf16(ah, bh, acc, 0, 0, 0);
      acc = __builtin_amdgcn_mfma_f32_32x32x16_bf16(al, bh, acc, 0, 0, 0);
      acc = __builtin_amdgcn_mfma_f32_32x32x16_bf16(ah, bl, acc, 0, 0, 0);
    }
    {
      const int nb = cb ^ 1;
      #pragma unroll
      for (int e = 0; e < 4; ++e) {
        ushort4 xh, xl, bh, bl;
        split4(xr[e], xh, xl); split4(br[e], bh, bl);
        *(ushort4*)&Xs[nb][0][srow][sc + e * 4] = xh;
        *(ushort4*)&Xs[nb][1][srow][sc + e * 4] = xl;
        *(ushort4*)&Bs[nb][0][srow][sc + e * 4] = bh;
        *(ushort4*)&Bs[nb][1][srow][sc + e * 4] = bl;
      }
    }
    __syncthreads();
  }
  float* out = Rp + (size_t)kc * ROWS * HARM;
  #pragma unroll
  for (int r = 0; r < 16; ++r) {
    int mloc = (r & 3) + 8 * (r >> 2) + 4 * hh;
    out[(size_t)(row0 + m0 + mloc) * HARM + n0 + l31] = acc[r];
  }
}

// --------------- O-path resonance: AO from bf16 hi/lo planes, basis_o fp32 split
// inline; software-pipelined. grid (64 Mtiles, 4 Kchunks).
__global__ __launch_bounds__(256) void gemm_res_o(
    const ushort* __restrict__ Xh, const ushort* __restrict__ Xl,
    const float* __restrict__ B, float* __restrict__ Rp) {
  const int row0 = blockIdx.x * 64;
  const int kc = blockIdx.y;
  __shared__ __align__(16) ushort Xs[2][2][64][72];
  __shared__ __align__(16) ushort Bs[2][2][64][72];
  const int t = threadIdx.x;
  const int lane = t & 63, w = t >> 6;
  const int l31 = lane & 31, hh = lane >> 5;
  const int m0 = (w & 1) * 32, n0 = (w >> 1) * 32;
  const int srow = t >> 2;
  const int sc = (t & 3) * 16;
  const size_t xrow = (size_t)(row0 + srow) * HIDDEN + sc;
  const size_t brow = (size_t)srow * HIDDEN + sc;
  f32x16 acc;
  #pragma unroll
  for (int j = 0; j < 16; ++j) acc[j] = 0.0f;

  uint4 xhr[2], xlr[2];
  float4 br[4];
  const int kbase = kc * 512;

  {
    const size_t xo = xrow + kbase;
    const float* bp = B + brow + kbase;
    xhr[0] = *(const uint4*)&Xh[xo]; xhr[1] = *(const uint4*)&Xh[xo + 8];
    xlr[0] = *(const uint4*)&Xl[xo]; xlr[1] = *(const uint4*)&Xl[xo + 8];
    #pragma unroll
    for (int e = 0; e < 4; ++e) br[e] = *(const float4*)&bp[e * 4];
    *(uint4*)&Xs[0][0][srow][sc]     = xhr[0];
    *(uint4*)&Xs[0][0][srow][sc + 8] = xhr[1];
    *(uint4*)&Xs[0][1][srow][sc]     = xlr[0];
    *(uint4*)&Xs[0][1][srow][sc + 8] = xlr[1];
    #pragma unroll
    for (int e = 0; e < 4; ++e) {
      ushort4 bh, bl;
      split4(br[e], bh, bl);
      *(ushort4*)&Bs[0][0][srow][sc + e * 4] = bh;
      *(ushort4*)&Bs[0][1][srow][sc + e * 4] = bl;
    }
  }
  __syncthreads();

  for (int it = 0; it < 8; ++it) {
    {
      const int kn = kbase + ((it < 7) ? (it + 1) : it) * 64;
      const size_t xo = xrow + kn;
      const float* bp = B + brow + kn;
      xhr[0] = *(const uint4*)&Xh[xo]; xhr[1] = *(const uint4*)&Xh[xo + 8];
      xlr[0] = *(const uint4*)&Xl[xo]; xlr[1] = *(const uint4*)&Xl[xo + 8];
      #pragma unroll
      for (int e = 0; e < 4; ++e) br[e] = *(const float4*)&bp[e * 4];
    }
    const int cb = it & 1;
    #pragma unroll
    for (int ks = 0; ks < 4; ++ks) {
      bf16x8 ah = *(const bf16x8*)&Xs[cb][0][m0 + l31][ks * 16 + 8 * hh];
      bf16x8 al = *(const bf16x8*)&Xs[cb][1][m0 + l31][ks * 16 + 8 * hh];
      bf16x8 bh = *(const bf16x8*)&Bs[cb][0][n0 + l31][ks * 16 + 8 * hh];
      bf16x8 bl = *(const bf16x8*)&Bs[cb][1][n0 + l31][ks * 16 + 8 * hh];
      acc = __builtin_amdgcn_mfma_f32_32x32x16_bf16(ah, bh, acc, 0, 0, 0);
      acc = __builtin_amdgcn_mfma_f32_32x32x16_bf16(al, bh, acc, 0, 0, 0);
      acc = __builtin_amdgcn_mfma_f32_32x32x16_bf16(ah, bl, acc, 0, 0, 0);
    }
    {
      const int nb = cb ^ 1;
      *(uint4*)&Xs[nb][0][srow][sc]     = xhr[0];
      *(uint4*)&Xs[nb][0][srow][sc + 8] = xhr[1];
      *(uint4*)&Xs[nb][1][srow][sc]     = xlr[0];
      *(uint4*)&Xs[nb][1][srow][sc + 8] = xlr[1];
      #pragma unroll
      for (int e = 0; e < 4; ++e) {
        ushort4 bh, bl;
        split4(br[e], bh, bl);
        *(ushort4*)&Bs[nb][0][srow][sc + e * 4] = bh;
        *(ushort4*)&Bs[nb][1][srow][sc + e * 4] = bl;
      }
    }
    __syncthreads();
  }
  float* out = Rp + (size_t)kc * ROWS * HARM;
  #pragma unroll
  for (int r = 0; r < 16; ++r) {
    int mloc = (r & 3) + 8 * (r >> 2) + 4 * hh;
    out[(size_t)(row0 + m0 + mloc) * HARM + n0 + l31] = acc[r];
  }
}

// --------------- MFMA projection (double-bf16): P = (sum_kc Rp) * W^T, bf16 out
// z=0 -> Qb, z=1 -> Kb, z=2 -> V written DIRECTLY TRANSPOSED into VtB (control).
__global__ __launch_bounds__(256) void gemm_proj(
    const float* __restrict__ Rp0, const float* __restrict__ Rp1,
    const float* __restrict__ Rp2,
    const ushort* __restrict__ Wh, const ushort* __restrict__ Wl,
    ushort* __restrict__ P0, ushort* __restrict__ P1, ushort* __restrict__ Vt) {
  const int z = blockIdx.z;
  const float* Rp = (z == 0) ? Rp0 : (z == 1) ? Rp1 : Rp2;
  const ushort* Whz = Wh + (size_t)z * HIDDEN * HARM;
  const ushort* Wlz = Wl + (size_t)z * HIDDEN * HARM;
  const int row0 = blockIdx.x * 32;
  const int col0 = blockIdx.y * 128;
  __shared__ __align__(16) union PSM {
    struct { ushort Rs[2][32][72]; ushort Ws[2][128][72]; } s;
    ushort ct[128][36];
  } sm;
  const int t = threadIdx.x;
  const int lane = t & 63, w = t >> 6;
  const int l31 = lane & 31, hh = lane >> 5;
  {
    const int r = t >> 3, h0 = (t & 7) * 8;
    const size_t o = (size_t)(row0 + r) * HARM + h0;
    #pragma unroll
    for (int e = 0; e < 8; ++e) {
      float v = Rp[o + e] + Rp[RN + o + e] + Rp[2 * (size_t)RN + o + e] +
                Rp[3 * (size_t)RN + o + e];
      ushort hi, lo;
      split_bf(v, hi, lo);
      sm.s.Rs[0][r][h0 + e] = hi;
      sm.s.Rs[1][r][h0 + e] = lo;
    }
  }
  #pragma unroll
  for (int i = 0; i < 4; ++i) {
    int idx = t + i * 256;
    int o = idx >> 3, c8 = (idx & 7) * 8;
    const size_t go = (size_t)(col0 + o) * HARM + c8;
    *(uint4*)&sm.s.Ws[0][o][c8] = *(const uint4*)&Whz[go];
    *(uint4*)&sm.s.Ws[1][o][c8] = *(const uint4*)&Wlz[go];
  }
  __syncthreads();
  const int n0 = w * 32;
  f32x16 acc;
  #pragma unroll
  for (int j = 0; j < 16; ++j) acc[j] = 0.0f;
  #pragma unroll
  for (int ks = 0; ks < 4; ++ks) {
    bf16x8 ah = *(const bf16x8*)&sm.s.Rs[0][l31][ks * 16 + 8 * hh];
    bf16x8 al = *(const bf16x8*)&sm.s.Rs[1][l31][ks * 16 + 8 * hh];
    bf16x8 bh = *(const bf16x8*)&sm.s.Ws[0][n0 + l31][ks * 16 + 8 * hh];
    bf16x8 bl = *(const bf16x8*)&sm.s.Ws[1][n0 + l31][ks * 16 + 8 * hh];
    acc = __builtin_amdgcn_mfma_f32_32x32x16_bf16(ah, bh, acc, 0, 0, 0);
    acc = __builtin_amdgcn_mfma_f32_32x32x16_bf16(al, bh, acc, 0, 0, 0);
    acc = __builtin_amdgcn_mfma_f32_32x32x16_bf16(ah, bl, acc, 0, 0, 0);
  }
  if (z < 2) {
    ushort* P = (z == 0) ? P0 : P1;
    #pragma unroll
    for (int r = 0; r < 16; ++r) {
      int mloc = (r & 3) + 8 * (r >> 2) + 4 * hh;
      union { __hip_bfloat16 b; ushort u; } cv;
      cv.b = __float2bfloat16(acc[r]);
      P[(size_t)(row0 + mloc) * HIDDEN + col0 + n0 + l31] = cv.u;
    }
  } else {
    __syncthreads();
    #pragma unroll
    for (int r = 0; r < 16; ++r) {
      int mloc = (r & 3) + 8 * (r >> 2) + 4 * hh;
      union { __hip_bfloat16 b; ushort u; } cv;
      cv.b = __float2bfloat16(acc[r]);
      sm.ct[n0 + l31][mloc] = cv.u;
    }
    __syncthreads();
    if (t < 128) {
      const int batch = row0 >> 11;
      const int tok0 = row0 & 2047;
      ushort* dst = Vt + (size_t)batch * SEQ * HIDDEN +
                    (size_t)(col0 + t) * SEQ + tok0;
      #pragma unroll
      for (int j = 0; j < 4; ++j)
        *(uint4*)&dst[j * 8] = *(const uint4*)&sm.ct[t][j * 8];
    }
  }
}

// --------------- MFMA final projection (double-bf16, fp32 out), grid (128, 16)
__global__ __launch_bounds__(256) void gemm_proj_f32(
    const float* __restrict__ Rp,
    const ushort* __restrict__ Whz, const ushort* __restrict__ Wlz,
    float* __restrict__ P) {
  const int row0 = blockIdx.x * 32;
  const int col0 = blockIdx.y * 128;
  __shared__ __align__(16) ushort Rs[2][32][72];
  __shared__ __align__(16) ushort Ws[2][128][72];
  const int t = threadIdx.x;
  const int lane = t & 63, w = t >> 6;
  const int l31 = lane & 31, hh = lane >> 5;
  {
    const int r = t >> 3, h0 = (t & 7) * 8;
    const size_t o = (size_t)(row0 + r) * HARM + h0;
    #pragma unroll
    for (int e = 0; e < 8; ++e) {
      float v = Rp[o + e] + Rp[RN + o + e] + Rp[2 * (size_t)RN + o + e] +
                Rp[3 * (size_t)RN + o + e];
      ushort hi, lo;
      split_bf(v, hi, lo);
      Rs[0][r][h0 + e] = hi;
      Rs[1][r][h0 + e] = lo;
    }
  }
  #pragma unroll
  for (int i = 0; i < 4; ++i) {
    int idx = t + i * 256;
    int o = idx >> 3, c8 = (idx & 7) * 8;
    const size_t go = (size_t)(col0 + o) * HARM + c8;
    *(uint4*)&Ws[0][o][c8] = *(const uint4*)&Whz[go];
    *(uint4*)&Ws[1][o][c8] = *(const uint4*)&Wlz[go];
  }
  __syncthreads();
  const int n0 = w * 32;
  f32x16 acc;
  #pragma unroll
  for (int j = 0; j < 16; ++j) acc[j] = 0.0f;
  #pragma unroll
  for (int ks = 0; ks < 4; ++ks) {
    bf16x8 ah = *(const bf16x8*)&Rs[0][l31][ks * 16 + 8 * hh];
    bf16x8 al = *(const bf16x8*)&Rs[1][l31][ks * 16 + 8 * hh];
    bf16x8 bh = *(const bf16x8*)&Ws[0][n0 + l31][ks * 16 + 8 * hh];
    bf16x8 bl = *(const bf16x8*)&Ws[1][n0 + l31][ks * 16 + 8 * hh];
    acc = __builtin_amdgcn_mfma_f32_32x32x16_bf16(ah, bh, acc, 0, 0, 0);
    acc = __builtin_amdgcn_mfma_f32_32x32x16_bf16(al, bh, acc, 0, 0, 0);
    acc = __builtin_amdgcn_mfma_f32_32x32x16_bf16(ah, bl, acc, 0, 0, 0);
  }
  #pragma unroll
  for (int r = 0; r < 16; ++r) {
    int mloc = (r & 3) + 8 * (r >> 2) + 4 * hh;
    P[(size_t)(row0 + mloc) * HIDDEN + col0 + n0 + l31] = acc[r];
  }
}

// ----------------------------------------------------------- MFMA flash attention
// R7 body; epilogue writes AO as bf16 hi/lo planes. UNCHANGED (control).
#define BQ 128
#define BK 64
#define KSTR 136
#define VSTR 72

__device__ inline unsigned pkbf(float a, float b) {
  __hip_bfloat162 h2 = __float22bfloat162_rn(make_float2(a, b));
  union { __hip_bfloat162 h; unsigned u; } cv; cv.h = h2; return cv.u;
}

__global__ __launch_bounds__(256, 2) void attn_mfma(
    const ushort* __restrict__ Qg, const ushort* __restrict__ Kg,
    const ushort* __restrict__ Vt, ushort* __restrict__ Oh,
    ushort* __restrict__ Ol) {
  __shared__ __align__(16) union SM {
    ushort q[BQ][KSTR];
    struct { ushort k[BK][KSTR]; ushort v[HDIM][VSTR]; } kv[2];
  } sm;
  const int t = threadIdx.x;
  const int bh = blockIdx.x & 31;
  const int qt = blockIdx.x >> 5;
  const int b = bh >> 4, h = bh & 15;
  const int q0 = qt * BQ;
  const int lane = t & 63;
  const int w = t >> 6;
  const int l31 = lane & 31;
  const int hh = lane >> 5;
  const bool hi = (hh != 0);
  const float SC2 = 0.08838834764831845f * 1.4426950408889634f;

  const int sk_key = t >> 4;
  const int sk_d0 = (t & 15) * 8;
  const int sv_d = t >> 3;
  const int sv_k = (t & 7) * 8;
  const size_t kbase = ((size_t)(b * SEQ)) * HIDDEN + h * HDIM;
  const size_t vbase = ((size_t)(b * SEQ + h * HDIM)) * SEQ;

  {
    const size_t gbase = ((size_t)(b * SEQ + q0)) * HIDDEN + h * HDIM;
    for (int p = 0; p < 8; ++p) {
      int row = p * 16 + sk_key;
      uint4 v = *(const uint4*)&Qg[gbase + (size_t)row * HIDDEN + sk_d0];
      *(uint4*)&sm.q[row][sk_d0] = v;
    }
  }
  __syncthreads();
  bf16x8 Qf[8];
  {
    const int qrow = w * 32 + l31;
    #pragma unroll
    for (int ks = 0; ks < 8; ++ks)
      Qf[ks] = *(const bf16x8*)&sm.q[qrow][ks * 16 + 8 * hh];
  }
  __syncthreads();

  float mrow = -1e30f, lsum = 0.0f;
  f32x16 Ot[4];
  #pragma unroll
  for (int i = 0; i < 4; ++i)
    #pragma unroll
    for (int j = 0; j < 16; ++j) Ot[i][j] = 0.0f;

  uint4 kp[4], vp[4];
  {
    const size_t gb = kbase;
    #pragma unroll
    for (int p = 0; p < 4; ++p)
      kp[p] = *(const uint4*)&Kg[gb + (size_t)(p * 16 + sk_key) * HIDDEN + sk_d0];
    #pragma unroll
    for (int p = 0; p < 4; ++p)
      vp[p] = *(const uint4*)&Vt[vbase + (size_t)(p * 32 + sv_d) * SEQ + sv_k];
    #pragma unroll
    for (int p = 0; p < 4; ++p)
      *(uint4*)&sm.kv[0].k[p * 16 + sk_key][sk_d0] = kp[p];
    #pragma unroll
    for (int p = 0; p < 4; ++p)
      *(uint4*)&sm.kv[0].v[p * 32 + sv_d][sv_k] = vp[p];
  }
  __syncthreads();

  for (int ci = 0; ci < 32; ++ci) {
    {
      const int cn = (ci < 31) ? ci + 1 : 31;
      const size_t gb = kbase + (size_t)(cn * BK) * HIDDEN;
      #pragma unroll
      for (int p = 0; p < 4; ++p)
        kp[p] = *(const uint4*)&Kg[gb + (size_t)(p * 16 + sk_key) * HIDDEN + sk_d0];
      const size_t vb = vbase + cn * BK;
      #pragma unroll
      for (int p = 0; p < 4; ++p)
        vp[p] = *(const uint4*)&Vt[vb + (size_t)(p * 32 + sv_d) * SEQ + sv_k];
    }
    const int cb = ci & 1;

    f32x16 C0, C1;
    #pragma unroll
    for (int j = 0; j < 16; ++j) { C0[j] = 0.0f; C1[j] = 0.0f; }
    #pragma unroll
    for (int ks = 0; ks < 8; ++ks) {
      bf16x8 a0 = *(const bf16x8*)&sm.kv[cb].k[l31][ks * 16 + 8 * hh];
      bf16x8 a1 = *(const bf16x8*)&sm.kv[cb].k[32 + l31][ks * 16 + 8 * hh];
      C0 = __builtin_amdgcn_mfma_f32_32x32x16_bf16(a0, Qf[ks], C0, 0, 0, 0);
      C1 = __builtin_amdgcn_mfma_f32_32x32x16_bf16(a1, Qf[ks], C1, 0, 0, 0);
    }

    float mxr = -1e30f;
    #pragma unroll
    for (int j = 0; j < 16; ++j) mxr = fmaxf(mxr, fmaxf(C0[j], C1[j]));
    mxr = fmaxf(mxr, __shfl_xor(mxr, 32));
    const float mnew = fmaxf(mrow, mxr * SC2);
    const float alpha = exp2f(mrow - mnew);
    float ssum = 0.0f;
    #pragma unroll
    for (int j = 0; j < 16; ++j) {
      float e0 = exp2f(fmaf(C0[j], SC2, -mnew));
      float e1 = exp2f(fmaf(C1[j], SC2, -mnew));
      C0[j] = e0; C1[j] = e1;
      ssum += e0 + e1;
    }
    ssum += __shfl_xor(ssum, 32);
    lsum = lsum * alpha + ssum;
    mrow = mnew;
    #pragma unroll
    for (int i = 0; i < 4; ++i)
      #pragma unroll
      for (int j = 0; j < 16; ++j) Ot[i][j] *= alpha;

    #pragma unroll
    for (int st = 0; st < 4; ++st) {
      const int eb = 8 * (st & 1);
      float o0, o1, o2, o3, g0, g1, g2, g3;
      if (st < 2) {
        o0 = hi ? C0[eb + 4] : C0[eb + 0]; o1 = hi ? C0[eb + 5] : C0[eb + 1];
        o2 = hi ? C0[eb + 6] : C0[eb + 2]; o3 = hi ? C0[eb + 7] : C0[eb + 3];
        g0 = hi ? C0[eb + 0] : C0[eb + 4]; g1 = hi ? C0[eb + 1] : C0[eb + 5];
        g2 = hi ? C0[eb + 2] : C0[eb + 6]; g3 = hi ? C0[eb + 3] : C0[eb + 7];
      } else {
        o0 = hi ? C1[eb + 4] : C1[eb + 0]; o1 = hi ? C1[eb + 5] : C1[eb + 1];
        o2 = hi ? C1[eb + 6] : C1[eb + 2]; o3 = hi ? C1[eb + 7] : C1[eb + 3];
        g0 = hi ? C1[eb + 0] : C1[eb + 4]; g1 = hi ? C1[eb + 1] : C1[eb + 5];
        g2 = hi ? C1[eb + 2] : C1[eb + 6]; g3 = hi ? C1[eb + 3] : C1[eb + 7];
      }
      unsigned so0 = pkbf(o0, o1), so1 = pkbf(o2, o3);
      unsigned sp0 = pkbf(g0, g1), sp1 = pkbf(g2, g3);
      unsigned r0 = (unsigned)__shfl_xor((int)sp0, 32);
      unsigned r1 = (unsigned)__shfl_xor((int)sp1, 32);
      union { unsigned u[4]; bf16x8 v; } cv;
      cv.u[0] = hi ? r0 : so0;
      cv.u[1] = hi ? r1 : so1;
      cv.u[2] = hi ? so0 : r0;
      cv.u[3] = hi ? so1 : r1;
      #pragma unroll
      for (int mt = 0; mt < 4; ++mt) {
        bf16x8 a2 = *(const bf16x8*)&sm.kv[cb].v[mt * 32 + l31][st * 16 + 8 * hh];
        Ot[mt] = __builtin_amdgcn_mfma_f32_32x32x16_bf16(a2, cv.v, Ot[mt], 0, 0, 0);
      }
    }

    {
      const int nb = cb ^ 1;
      #pragma unroll
      for (int p = 0; p < 4; ++p)
        *(uint4*)&sm.kv[nb].k[p * 16 + sk_key][sk_d0] = kp[p];
      #pragma unroll
      for (int p = 0; p < 4; ++p)
        *(uint4*)&sm.kv[nb].v[p * 32 + sv_d][sv_k] = vp[p];
    }
    __syncthreads();
  }

  // ---- epilogue: normalized AO as bf16 hi/lo planes
  const float inv = 1.0f / lsum;
  const int qrow = q0 + w * 32 + l31;
  const size_t ob = ((size_t)(b * SEQ + qrow)) * HIDDEN + h * HDIM;
  #pragma unroll
  for (int mt = 0; mt < 4; ++mt)
    #pragma unroll
    for (int g = 0; g < 4; ++g) {
      ushort4 hs, ls;
      split_bf(Ot[mt][4 * g + 0] * inv, hs.x, ls.x);
      split_bf(Ot[mt][4 * g + 1] * inv, hs.y, ls.y);
      split_bf(Ot[mt][4 * g + 2] * inv, hs.z, ls.z);
      split_bf(Ot[mt][4 * g + 3] * inv, hs.w, ls.w);
      const size_t off = ob + mt * 32 + 8 * g + 4 * hh;
      *(ushort4*)&Oh[off] = hs;
      *(ushort4*)&Ol[off] = ls;
    }
}

// -------------------------------------------------------------------------- launcher
extern "C" void kernel_launch(void* const* d_in, const int* in_sizes, int n_in,
                              void* d_out, int out_size, void* d_ws, size_t ws_size,
                              hipStream_t stream) {
  (void)in_sizes; (void)n_in; (void)out_size; (void)ws_size;
  const float* X       = (const float*)d_in[0];
  const float* basis_q = (const float*)d_in[1];
  const float* phase_q = (const float*)d_in[2];
  const float* amp_q   = (const float*)d_in[3];
  const float* basis_k = (const float*)d_in[4];
  const float* phase_k = (const float*)d_in[5];
  const float* amp_k   = (const float*)d_in[6];
  const float* basis_v = (const float*)d_in[7];
  const float* phase_v = (const float*)d_in[8];
  const float* amp_v   = (const float*)d_in[9];
  const float* basis_o = (const float*)d_in[10];
  const float* phase_o = (const float*)d_in[11];
  const float* amp_o   = (const float*)d_in[12];

  const size_t WN = (size_t)HIDDEN * HARM;   // 131072

  char* p = (char*)d_ws;
  ushort* Whi = (ushort*)p; p += 4 * WN * 2;
  ushort* Wlo = (ushort*)p; p += 4 * WN * 2;
  float* Rqp = (float*)p; p += (size_t)4 * RN * 4;
  float* Rkp = (float*)p; p += (size_t)4 * RN * 4;
  float* Rvp = (float*)p; p += (size_t)4 * RN * 4;
  float* Rop = (float*)p; p += (size_t)4 * RN * 4;
  __hip_bfloat16* Qb = (__hip_bfloat16*)p; p += PN * 2;
  __hip_bfloat16* Kb = (__hip_bfloat16*)p; p += PN * 2;
  __hip_bfloat16* VtB = (__hip_bfloat16*)p; p += PN * 2;
  ushort* AOh = (ushort*)p; p += PN * 2;
  ushort* AOl = (ushort*)p; p += PN * 2;
  float* out = (float*)d_out;

  prep_w<<<2048, 256, 0, stream>>>(phase_q, amp_q, phase_k, amp_k,
                                   phase_v, amp_v, phase_o, amp_o,
                                   Whi, Wlo);

  gemm_res_f32<<<dim3(64, 4, 3), 256, 0, stream>>>(
      X, basis_q, basis_k, basis_v, Rqp, Rkp, Rvp);

  gemm_proj<<<dim3(128, 16, 3), 256, 0, stream>>>(
      Rqp, Rkp, Rvp, Whi, Wlo, (ushort*)Qb, (ushort*)Kb, (ushort*)VtB);

  attn_mfma<<<dim3((SEQ / BQ) * 32), 256, 0, stream>>>(
      (const ushort*)Qb, (const ushort*)Kb, (const ushort*)VtB, AOh, AOl);

  gemm_res_o<<<dim3(64, 4), 256, 0, stream>>>(AOh, AOl, basis_o, Rop);

  gemm_proj_f32<<<dim3(128, 16), 256, 0, stream>>>(
      Rop, Whi + 3 * WN, Wlo + 3 * WN, out);
}